// Round 10
// baseline (604.966 us; speedup 1.0000x reference)
//
#include <hip/hip_runtime.h>

#define DI __device__ __forceinline__

typedef __attribute__((ext_vector_type(8))) __bf16 bf16x8;
typedef __attribute__((ext_vector_type(4))) float f32x4;
typedef __attribute__((ext_vector_type(8))) unsigned short ushort8;
typedef unsigned long long ull;

static DI unsigned short f2b(float f) {
  unsigned int x = __builtin_bit_cast(unsigned int, f);
  unsigned int r = (x + 0x7FFFu + ((x >> 16) & 1u)) >> 16;
  return (unsigned short)r;
}
static DI float b2f(unsigned short u) {
  return __builtin_bit_cast(float, (unsigned int)u << 16);
}
static DI float sigmf(float x) { return 1.0f / (1.0f + __expf(-x)); }

typedef const __attribute__((address_space(1))) void* gcptr;
typedef __attribute__((address_space(3))) void* lptr;
static DI void gl_lds16(const void* g, void* l) {
  __builtin_amdgcn_global_load_lds((gcptr)g, (lptr)l, 16, 0, 0);
}

// gate-interleaved column (16-granular): gate g, dim d -> raw col in [0,2048)
#define GCOL(g, d) ((((d) >> 4) << 6) + ((g) << 4) + ((d) & 15))

// packed-C quad address (b64 units): rows 4*row4..4*row4+3, col c; NT = N/128
static DI size_t qaddr(int NT, int row4, int c) {
  int tm = row4 >> 5, tn = c >> 7;
  int rq = row4 & 31, c7 = c & 127;
  int wv = ((rq >> 4) << 1) | (c7 >> 6);
  int mf = (rq >> 2) & 3, nf = (c7 >> 4) & 3;
  int lane = ((rq & 3) << 4) | (c7 & 15);
  return ((size_t)(tm * NT + tn) << 12) + (size_t)((((wv << 4) + (mf << 2) + nf) << 6) + lane);
}

// ---------------- weight packing ---------------------------------------------
__global__ void prep_pack(const float* __restrict__ Wi, const float* __restrict__ Ui,
                          const float* __restrict__ bi, const float* __restrict__ Wf,
                          const float* __restrict__ Uf, const float* __restrict__ bfv,
                          const float* __restrict__ Wo, const float* __restrict__ Uo,
                          const float* __restrict__ bo, const float* __restrict__ Wu,
                          const float* __restrict__ Uu, const float* __restrict__ bu,
                          unsigned short* __restrict__ Wp, unsigned short* __restrict__ Upiou,
                          unsigned short* __restrict__ Upf, float* __restrict__ bias)
{
  int u = blockIdx.x * blockDim.x + threadIdx.x;  // 0..262143
  if (u < 131072) {            // Wp: [64][2048][8], 16-granular gate-interleaved cols
    int k8 = u >> 11, n = u & 2047;
    int gate = (n >> 4) & 3;
    int d = ((n >> 6) << 4) | (n & 15);
    const float* W = (gate == 0) ? Wi : (gate == 1) ? Wf : (gate == 2) ? Wo : Wu;
    ushort8 pk;
    #pragma unroll
    for (int t = 0; t < 8; ++t) pk[t] = f2b(W[(size_t)(k8*8+t)*512 + d]);
    *(ushort8*)&Wp[(size_t)u*8] = pk;
  } else if (u < 131072 + 98304) {  // Upiou: [64][1536][8], cols = [Ui|Uo|Uu]
    int v = u - 131072;
    int k8 = v / 1536, n = v - k8*1536;
    const float* U = (n < 512) ? Ui : (n < 1024) ? Uo : Uu;
    int c = n & 511;
    ushort8 pk;
    #pragma unroll
    for (int t = 0; t < 8; ++t) pk[t] = f2b(U[(size_t)(k8*8+t)*512 + c]);
    *(ushort8*)&Upiou[(size_t)v*8] = pk;
  } else {                     // Upf: [64][512][8]
    int v = u - 229376;
    int k8 = v >> 9, c = v & 511;
    ushort8 pk;
    #pragma unroll
    for (int t = 0; t < 8; ++t) pk[t] = f2b(Uf[(size_t)(k8*8+t)*512 + c]);
    *(ushort8*)&Upf[(size_t)v*8] = pk;
  }
  if (u < 2048) {              // bias, interleaved to match Wp
    int gate = (u >> 4) & 3;
    int d = ((u >> 6) << 4) | (u & 15);
    bias[u] = (gate == 0) ? bi[d] : (gate == 1) ? bfv[d] : (gate == 2) ? bo[d] : bu[d];
  }
}

// ---------------- gather emb rows -> X bf16 [22272][512] (level-padded) -----
__global__ void gather_x(const int* __restrict__ tok, const float* __restrict__ emb,
                         unsigned short* __restrict__ X)
{
  int u = blockIdx.x * blockDim.x + threadIdx.x;  // unit = 8 elems
  if (u >= 22272*64) return;
  int R = u >> 6, ch = u & 63;
  int l, node;
  if (R < 512)       { l = R >> 7; node = R & 127; int sz = 1 << (2*l); if (node >= sz) node = sz - 1; }
  else if (R < 768)  { l = 4; node = R - 512; }
  else if (R < 1792) { l = 5; node = R - 768; }
  else if (R < 5888) { l = 6; node = R - 1792; }
  else               { l = 7; node = R - 5888; }
  static const int offs_c[8] = {0,1,5,21,85,341,1365,5461};
  int tk = tok[offs_c[l] + node];
  const float* src = emb + (size_t)tk*512 + ch*8;
  ushort8 pk;
  #pragma unroll
  for (int t = 0; t < 8; ++t) pk[t] = f2b(src[t]);
  *(ushort8*)&X[(size_t)u*8] = pk;
}

// ------- hybrid bf16 MFMA GEMM: A via LDS dbuf, B direct from L2 -------------
struct GDesc {
  const unsigned short* A;   // [M][512] bf16 row-major
  const unsigned short* Bp;  // packed [64][N][8]
  ull* C;                    // fragment-packed (qaddr) output
  int M, N, NT;              // NT = N/128
};
struct L7P {                 // fused level-7 outputs (FUSED only)
  float* hout; unsigned short* hb; float* cb; unsigned short* ht;
};

template<bool FUSED>
__global__ __launch_bounds__(256, 4)
void gemm512(GDesc g1, GDesc g2, int split, const float* __restrict__ bias, L7P l7,
             float* __restrict__ zbase, size_t z4)
{
  __shared__ unsigned short As[2*128*64];   // 32 KB total (A only)

  const int nwg = gridDim.x, orig = blockIdx.x;
  const int q = nwg >> 3, r = nwg & 7;
  const int xcd = orig & 7, idx = orig >> 3;
  const int wg = (xcd < r ? xcd*(q+1) : r*(q+1) + (xcd-r)*q) + idx;

  const bool role1 = (wg < split);
  GDesc g = role1 ? g1 : g2;
  const int lwg = role1 ? wg : wg - split;
  const int tm = lwg / g.NT, tn = lwg - tm * g.NT;

  const int tid = threadIdx.x;
  const int wave = tid >> 6, lane = tid & 63;
  const int Mbase = tm * 128, Nbase = tn * 128;
  const int wr = wave >> 1, wc = wave & 1;
  const int l15 = lane & 15, l4 = lane >> 4;

  const int arow_l = wave*8 + (lane >> 3);
  const int acol8  = lane & 7;
  const int sw8    = arow_l & 7;

  f32x4 acc[4][4] = {};

  auto STAGE = [&](int p, int k0) {
    #pragma unroll
    for (int c = 0; c < 4; ++c) {
      int grow = Mbase + c*32 + arow_l;
      if (grow >= g.M) grow = g.M - 1;
      gl_lds16(g.A + (size_t)grow*512 + k0 + ((acol8 ^ sw8) * 8),
               As + p*(128*64) + (c*32 + wave*8)*64);
    }
  };

  auto COMPUTE = [&](int p, int k0) {
    #pragma unroll
    for (int ks = 0; ks < 2; ++ks) {
      bf16x8 af[4], bfr[4];
      #pragma unroll
      for (int nf = 0; nf < 4; ++nf)     // B direct from L2 (no barrier dep)
        bfr[nf] = *(const bf16x8*)(g.Bp +
            ((size_t)((k0 >> 3) + ks*4 + l4) * g.N + Nbase + wc*64 + nf*16 + l15) * 8);
      #pragma unroll
      for (int mf = 0; mf < 4; ++mf) {
        int row = wr*64 + mf*16 + l15;
        int kc  = ks*4 + l4;
        af[mf] = *(const bf16x8*)&As[p*(128*64) + row*64 + ((kc ^ (row & 7)) * 8)];
      }
      #pragma unroll
      for (int mf = 0; mf < 4; ++mf)
        #pragma unroll
        for (int nf = 0; nf < 4; ++nf)
          acc[mf][nf] = __builtin_amdgcn_mfma_f32_16x16x32_bf16(af[mf], bfr[nf], acc[mf][nf], 0, 0, 0);
    }
  };

  STAGE(0, 0);
  __syncthreads();
  #pragma unroll
  for (int it = 0; it < 7; ++it) {
    STAGE((it + 1) & 1, (it + 1) * 64);
    COMPUTE(it & 1, it * 64);
    __syncthreads();
  }
  COMPUTE(1, 448);

  if (FUSED && tm >= 46) {
    // ---- fused level-7 combine, in registers (leaves: c=i*u, h=o*tanh(c))
    const float bi_ = bias[Nbase + wc*64      + l15];
    const float bo_ = bias[Nbase + wc*64 + 32 + l15];
    const float bu_ = bias[Nbase + wc*64 + 48 + l15];
    const int d = tn*32 + wc*16 + l15;
    #pragma unroll
    for (int mf = 0; mf < 4; ++mf) {
      int node0 = Mbase - 5888 + wr*64 + mf*16 + l4*4;
      float hts = 0.f;
      #pragma unroll
      for (int rr = 0; rr < 4; ++rr) {
        float iv = sigmf(acc[mf][0][rr] + bi_);
        float ov = sigmf(acc[mf][2][rr] + bo_);
        float uv = tanhf(acc[mf][3][rr] + bu_);
        float cv = iv * uv;
        float hv = ov * tanhf(cv);
        size_t node = node0 + rr;
        l7.hout[node*512 + d] = hv;
        l7.hb[node*512 + d]   = f2b(hv);
        l7.cb[node*512 + d]   = cv;
        hts += hv;
      }
      l7.ht[(size_t)(node0 >> 2)*512 + d] = f2b(hts);
    }
  } else {
    float bv[4];
    #pragma unroll
    for (int nf = 0; nf < 4; ++nf)
      bv[nf] = (bias != nullptr && role1) ? bias[Nbase + wc*64 + nf*16 + l15] : 0.f;
    ull* Cb = g.C + ((size_t)(tm * g.NT + tn) << 12) + ((size_t)wave << 10);
    #pragma unroll
    for (int mf = 0; mf < 4; ++mf)
      #pragma unroll
      for (int nf = 0; nf < 4; ++nf) {
        f32x4 a = acc[mf][nf];
        ull pk = (ull)f2b(a[0] + bv[nf]) | ((ull)f2b(a[1] + bv[nf]) << 16)
               | ((ull)f2b(a[2] + bv[nf]) << 32) | ((ull)f2b(a[3] + bv[nf]) << 48);
        Cb[(mf*4 + nf)*64 + lane] = pk;
      }
  }

  if (zbase != nullptr) {       // leaf-region zeros on spare write BW
    f32x4 z = {0.f, 0.f, 0.f, 0.f};
    f32x4* zp = (f32x4*)zbase;
    size_t stride = (size_t)nwg * 256;
    for (size_t off = (size_t)orig*256 + tid; off < z4; off += stride) zp[off] = z;
  }
}

// ---------------- direct-register tile GEMM (levels 4,3) ---------------------
static DI void tile_gemm(const unsigned short* __restrict__ A, int M,
                         const unsigned short* __restrict__ Bp, int N, int NT,
                         int tm, int tn, ull* __restrict__ C, int wave, int lane)
{
  const int wr = wave >> 1, wc = wave & 1;
  const int l15 = lane & 15, l4 = lane >> 4;
  size_t a0[4]; unsigned int b0[4];
  #pragma unroll
  for (int mf = 0; mf < 4; ++mf) {
    int row = tm*128 + wr*64 + mf*16 + l15;
    if (row >= M) row = M - 1;
    a0[mf] = (size_t)row*512 + l4*8;
  }
  #pragma unroll
  for (int nf = 0; nf < 4; ++nf)
    b0[nf] = (unsigned int)(((unsigned)l4 * N + tn*128 + wc*64 + nf*16 + l15) * 8);
  const unsigned int bstep = (unsigned int)N * 32;

  f32x4 acc[4][4] = {};
  #pragma unroll
  for (int ks = 0; ks < 16; ++ks) {
    bf16x8 af[4], bfr[4];
    #pragma unroll
    for (int mf = 0; mf < 4; ++mf) af[mf] = *(const bf16x8*)(A + a0[mf] + ks*32);
    #pragma unroll
    for (int nf = 0; nf < 4; ++nf) bfr[nf] = *(const bf16x8*)(Bp + b0[nf] + ks*bstep);
    #pragma unroll
    for (int mf = 0; mf < 4; ++mf)
      #pragma unroll
      for (int nf = 0; nf < 4; ++nf)
        acc[mf][nf] = __builtin_amdgcn_mfma_f32_16x16x32_bf16(af[mf], bfr[nf], acc[mf][nf], 0, 0, 0);
  }
  ull* Cb = C + ((size_t)(tm * NT + tn) << 12) + ((size_t)wave << 10);
  #pragma unroll
  for (int mf = 0; mf < 4; ++mf)
    #pragma unroll
    for (int nf = 0; nf < 4; ++nf) {
      f32x4 a = acc[mf][nf];
      ull pk = (ull)f2b(a[0]) | ((ull)f2b(a[1]) << 16)
             | ((ull)f2b(a[2]) << 32) | ((ull)f2b(a[3]) << 48);
      Cb[(mf*4 + nf)*64 + lane] = pk;
    }
}

__global__ __launch_bounds__(256)
void gemm_small(GDesc g1, GDesc g2, int split)
{
  const int b = blockIdx.x;
  const bool role1 = (b < split);
  GDesc g = role1 ? g1 : g2;
  const int lb = role1 ? b : b - split;
  tile_gemm(g.A, g.M, g.Bp, g.N, g.NT, lb / g.NT, lb % g.NT, g.C,
            threadIdx.x >> 6, threadIdx.x & 63);
}

// ---------------- shared combine body (packed-C inputs) ----------------------
static DI void combine_body(const ull* Gq, const ull* Rq, const ull* Fq,
                            const float* cch, float* hout, unsigned short* hbf,
                            float* cout, unsigned short* htout, float* rootx,
                            int n, int b, int t)
{
  #pragma unroll
  for (int half = 0; half < 2; ++half) {
    const int c = t + half * 256;
    ull gi4 = Gq[qaddr(16, b, GCOL(0, c))];
    ull gf4 = Gq[qaddr(16, b, GCOL(1, c))];
    ull go4 = Gq[qaddr(16, b, GCOL(2, c))];
    ull gu4 = Gq[qaddr(16, b, GCOL(3, c))];
    ull ri4 = Rq[qaddr(12, b, c)];
    ull ro4 = Rq[qaddr(12, b, c + 512)];
    ull ru4 = Rq[qaddr(12, b, c + 1024)];
    float hts = 0.f;
    #pragma unroll
    for (int rI = 0; rI < 4; ++rI) {
      int j = b*4 + rI;
      float gi = b2f((unsigned short)(gi4 >> (16*rI)));
      float gf = b2f((unsigned short)(gf4 >> (16*rI)));
      float go = b2f((unsigned short)(go4 >> (16*rI)));
      float gu = b2f((unsigned short)(gu4 >> (16*rI)));
      float iv = sigmf(gi + b2f((unsigned short)(ri4 >> (16*rI))));
      float ov = sigmf(go + b2f((unsigned short)(ro4 >> (16*rI))));
      float uv = tanhf(gu + b2f((unsigned short)(ru4 >> (16*rI))));
      ull f4 = Fq[qaddr(4, j, c)];
      const float* cc = cch + (size_t)(j*4)*512 + c;
      float fs = 0.f;
      #pragma unroll
      for (int k = 0; k < 4; ++k)
        fs += sigmf(gf + b2f((unsigned short)(f4 >> (16*k)))) * cc[(size_t)k*512];
      float cv = iv*uv + fs;
      float hv = ov * tanhf(cv);
      if (j < n) {
        hout[(size_t)j*512 + c] = hv;
        hbf[(size_t)j*512 + c]  = f2b(hv);
        cout[(size_t)j*512 + c] = cv;
        if (rootx && j == 0) { rootx[c] = hv; rootx[512 + c] = cv; }
        hts += hv;
      }
    }
    if (htout) htout[(size_t)b*512 + c] = f2b(hts);
  }
}

__global__ __launch_bounds__(256)
void combine2(const ull* Gq, const ull* Rq, const ull* Fq, const float* cch,
              float* hout, unsigned short* hbf, float* cout,
              unsigned short* htout, float* rootx, int n)
{
  combine_body(Gq, Rq, Fq, cch, hout, hbf, cout, htout, rootx, n,
               blockIdx.x, threadIdx.x);
}

// ---------------- single-block tail: levels 2..0 -----------------------------
__global__ __launch_bounds__(256)
void tail(unsigned short* hbf, unsigned short* htbf, float* cbuf,
          const unsigned short* Upiou, const unsigned short* Upf,
          ull* RiouQ, ull* RfQ, const ull* Gq, float* fout)
{
  static const int offs_c[9]   = {0,1,5,21,85,341,1365,5461,21845};
  static const int padbase_c[8]= {0,128,256,384,512,768,1792,5888};
  static const int outoff_c[8] = {87380,87376,87360,87296,87040,86016,81920,65536};
  const int t = threadIdx.x, wave = t >> 6, lane = t & 63;
  const int l15 = lane & 15, l4 = lane >> 4;

  for (int l = 2; l >= 0; --l) {
    const int n = 1 << (2*l);
    const int T1 = ((n + 15) >> 4) * 96;          // iou wave-tiles (N=1536)
    const int T2 = ((4*n + 15) >> 4) * 32;        // f wave-tiles (N=512)
    for (int tt = wave; tt < T1 + T2; tt += 4) {
      const unsigned short* A; const unsigned short* Bp; ull* C;
      int M, N, NT, tm16, tn16;
      if (tt < T1) {
        A = htbf + (size_t)offs_c[l]*512; M = n; Bp = Upiou; N = 1536; NT = 12;
        tm16 = tt / 96; tn16 = tt - tm16*96; C = RiouQ;
      } else {
        int u = tt - T1;
        A = hbf + (size_t)offs_c[l+1]*512; M = 4*n; Bp = Upf; N = 512; NT = 4;
        tm16 = u / 32; tn16 = u - tm16*32; C = RfQ;
      }
      int row = tm16*16 + l15; if (row >= M) row = M - 1;
      int col = tn16*16 + l15;
      f32x4 acc = {0.f, 0.f, 0.f, 0.f};
      #pragma unroll
      for (int m = 0; m < 16; ++m) {
        bf16x8 af = *(const bf16x8*)(A + (size_t)row*512 + (m*4 + l4)*8);
        bf16x8 bf_ = *(const bf16x8*)(Bp + ((size_t)(m*4 + l4)*N + col)*8);
        acc = __builtin_amdgcn_mfma_f32_16x16x32_bf16(af, bf_, acc, 0, 0, 0);
      }
      ull pk = (ull)f2b(acc[0]) | ((ull)f2b(acc[1]) << 16)
             | ((ull)f2b(acc[2]) << 32) | ((ull)f2b(acc[3]) << 48);
      C[qaddr(NT, tm16*4 + l4, col)] = pk;
    }
    __syncthreads();
    const int groups = (n + 3) >> 2;
    for (int b = 0; b < groups; ++b)
      combine_body(Gq + (size_t)padbase_c[l]*512, RiouQ, RfQ,
                   cbuf + (size_t)offs_c[l+1]*512,
                   fout + (size_t)outoff_c[l]*512,
                   hbf + (size_t)offs_c[l]*512,
                   cbuf + (size_t)offs_c[l]*512,
                   (l > 0) ? htbf + (size_t)offs_c[l-1]*512 : nullptr,
                   (l == 0) ? fout + (size_t)87381*512 : nullptr,
                   n, b, t);
    __syncthreads();
  }
}

// ---------------- launch -----------------------------------------------------
extern "C" void kernel_launch(void* const* d_in, const int* in_sizes, int n_in,
                              void* d_out, int out_size, void* d_ws, size_t ws_size,
                              hipStream_t stream)
{
  const int*   tok = (const int*)d_in[0];
  const float* emb = (const float*)d_in[1];
  const float* Wi  = (const float*)d_in[2];
  const float* Ui  = (const float*)d_in[3];
  const float* bi  = (const float*)d_in[4];
  const float* Wf  = (const float*)d_in[5];
  const float* Uf  = (const float*)d_in[6];
  const float* bfv = (const float*)d_in[7];
  const float* Wo  = (const float*)d_in[8];
  const float* Uo  = (const float*)d_in[9];
  const float* bo  = (const float*)d_in[10];
  const float* Wu  = (const float*)d_in[11];
  const float* Uu  = (const float*)d_in[12];
  const float* bu  = (const float*)d_in[13];

  char* ws = (char*)d_ws;
  unsigned short* Wp    = (unsigned short*)(ws + 0);           //  2,097,152
  unsigned short* Upiou = (unsigned short*)(ws + 2097152);     //  1,572,864
  unsigned short* Upf   = (unsigned short*)(ws + 3670016);     //    524,288
  float*          bias  = (float*)        (ws + 4194304);      //      8,192
  unsigned short* hbf   = (unsigned short*)(ws + 4202752);     // 22,369,280
  unsigned short* htbf  = (unsigned short*)(ws + 26572032);    //  5,592,064
  float*          cbuf  = (float*)        (ws + 32164096);     // 44,738,560
  ull*            RiouQ = (ull*)          (ws + 76902656);     // 12,582,912
  ull*            RfQ   = (ull*)          (ws + 89485568);     // 16,777,216
  ull*            Gq    = (ull*)          (ws + 106262784);    // 24,117,248 (46 row-tiles)
  unsigned short* X     = (unsigned short*)(ws + 130380032);   // 22,806,528 -> 153,186,560

  float* fout = (float*)d_out;

  static const int  offs[9]    = {0,1,5,21,85,341,1365,5461,21845};
  static const int  padbase[8] = {0,128,256,384,512,768,1792,5888};
  static const long outoff[8]  = {87380,87376,87360,87296,87040,86016,81920,65536};

  prep_pack<<<1024, 256, 0, stream>>>(Wi,Ui,bi,Wf,Uf,bfv,Wo,Uo,bo,Wu,Uu,bu,
                                      Wp,Upiou,Upf,bias);
  gather_x<<<(22272*64)/256, 256, 0, stream>>>(tok, emb, X);

  // big GEMM: gates for all internal nodes; fused level-7 combine (register)
  GDesc gA { X, Wp, Gq, 22272, 2048, 16 };
  L7P l7 { fout + (size_t)outoff[7]*512, hbf + (size_t)offs[7]*512,
           cbuf + (size_t)offs[7]*512, htbf + (size_t)offs[6]*512 };
  gemm512<true><<<174*16, 256, 0, stream>>>(gA, gA, 174*16, bias, l7, nullptr, 0);

  L7P l7n {};
  // level 6 (carries the 134 MB leaf zero-fill on spare write BW)
  {
    GDesc g1 { htbf + (size_t)offs[6]*512, Upiou, RiouQ, 4096,  1536, 12 };
    GDesc g2 { hbf  + (size_t)offs[7]*512, Upf,   RfQ,   16384, 512,  4  };
    gemm512<false><<<32*12 + 128*4, 256, 0, stream>>>(g1, g2, 32*12, nullptr, l7n,
                                                      fout, (size_t)65536*512/4);
    combine2<<<1024, 256, 0, stream>>>(
        Gq + (size_t)padbase[6]*512, RiouQ, RfQ, cbuf + (size_t)offs[7]*512,
        fout + (size_t)outoff[6]*512, hbf + (size_t)offs[6]*512, cbuf + (size_t)offs[6]*512,
        htbf + (size_t)offs[5]*512, nullptr, 4096);
  }
  // level 5
  {
    GDesc g1 { htbf + (size_t)offs[5]*512, Upiou, RiouQ, 1024, 1536, 12 };
    GDesc g2 { hbf  + (size_t)offs[6]*512, Upf,   RfQ,   4096, 512,  4  };
    gemm512<false><<<8*12 + 32*4, 256, 0, stream>>>(g1, g2, 8*12, nullptr, l7n, nullptr, 0);
    combine2<<<256, 256, 0, stream>>>(
        Gq + (size_t)padbase[5]*512, RiouQ, RfQ, cbuf + (size_t)offs[6]*512,
        fout + (size_t)outoff[5]*512, hbf + (size_t)offs[5]*512, cbuf + (size_t)offs[5]*512,
        htbf + (size_t)offs[4]*512, nullptr, 1024);
  }
  // levels 4,3: direct-register tile GEMM + combine
  for (int l = 4; l >= 3; --l) {
    int n = 1 << (2*l);
    int t1 = ((n + 127) >> 7) * 12;
    int t2 = ((4*n + 127) >> 7) * 4;
    GDesc g1 { htbf + (size_t)offs[l]*512,   Upiou, RiouQ, n,   1536, 12 };
    GDesc g2 { hbf  + (size_t)offs[l+1]*512, Upf,   RfQ,   4*n, 512,  4  };
    gemm_small<<<t1 + t2, 256, 0, stream>>>(g1, g2, t1);
    combine2<<<(n + 3) / 4, 256, 0, stream>>>(
        Gq + (size_t)padbase[l]*512, RiouQ, RfQ, cbuf + (size_t)offs[l+1]*512,
        fout + (size_t)outoff[l]*512, hbf + (size_t)offs[l]*512, cbuf + (size_t)offs[l]*512,
        htbf + (size_t)offs[l-1]*512, nullptr, n);
  }
  // levels 2..0: one single-block kernel
  tail<<<1, 256, 0, stream>>>(hbf, htbf, cbuf, Upiou, Upf, RiouQ, RfQ, Gq, fout);
}

// Round 11
// 277.939 us; speedup vs baseline: 2.1766x; 2.1766x over previous
//
#include <hip/hip_runtime.h>

#define DI __device__ __forceinline__

typedef __attribute__((ext_vector_type(8))) __bf16 bf16x8;
typedef __attribute__((ext_vector_type(4))) float f32x4;
typedef __attribute__((ext_vector_type(8))) unsigned short ushort8;
typedef unsigned long long ull;

static DI unsigned short f2b(float f) {
  unsigned int x = __builtin_bit_cast(unsigned int, f);
  unsigned int r = (x + 0x7FFFu + ((x >> 16) & 1u)) >> 16;
  return (unsigned short)r;
}
static DI float b2f(unsigned short u) {
  return __builtin_bit_cast(float, (unsigned int)u << 16);
}
static DI float sigmf(float x) { return 1.0f / (1.0f + __expf(-x)); }

typedef const __attribute__((address_space(1))) void* gcptr;
typedef __attribute__((address_space(3))) void* lptr;
static DI void gl_lds16(const void* g, void* l) {
  __builtin_amdgcn_global_load_lds((gcptr)g, (lptr)l, 16, 0, 0);
}

// gate-interleaved column (16-granular): gate g, dim d -> raw col in [0,2048)
#define GCOL(g, d) ((((d) >> 4) << 6) + ((g) << 4) + ((d) & 15))

// packed-C quad address (b64 units): rows 4*row4..4*row4+3, col c; NT = N/128
static DI size_t qaddr(int NT, int row4, int c) {
  int tm = row4 >> 5, tn = c >> 7;
  int rq = row4 & 31, c7 = c & 127;
  int wv = ((rq >> 4) << 1) | (c7 >> 6);
  int mf = (rq >> 2) & 3, nf = (c7 >> 4) & 3;
  int lane = ((rq & 3) << 4) | (c7 & 15);
  return ((size_t)(tm * NT + tn) << 12) + (size_t)((((wv << 4) + (mf << 2) + nf) << 6) + lane);
}

// ---------------- weight packing ---------------------------------------------
__global__ void prep_pack(const float* __restrict__ Wi, const float* __restrict__ Ui,
                          const float* __restrict__ bi, const float* __restrict__ Wf,
                          const float* __restrict__ Uf, const float* __restrict__ bfv,
                          const float* __restrict__ Wo, const float* __restrict__ Uo,
                          const float* __restrict__ bo, const float* __restrict__ Wu,
                          const float* __restrict__ Uu, const float* __restrict__ bu,
                          unsigned short* __restrict__ Wp, unsigned short* __restrict__ Upiou,
                          unsigned short* __restrict__ Upf, float* __restrict__ bias)
{
  int u = blockIdx.x * blockDim.x + threadIdx.x;  // 0..262143
  if (u < 131072) {            // Wp: [64][2048][8], 16-granular gate-interleaved cols
    int k8 = u >> 11, n = u & 2047;
    int gate = (n >> 4) & 3;
    int d = ((n >> 6) << 4) | (n & 15);
    const float* W = (gate == 0) ? Wi : (gate == 1) ? Wf : (gate == 2) ? Wo : Wu;
    ushort8 pk;
    #pragma unroll
    for (int t = 0; t < 8; ++t) pk[t] = f2b(W[(size_t)(k8*8+t)*512 + d]);
    *(ushort8*)&Wp[(size_t)u*8] = pk;
  } else if (u < 131072 + 98304) {  // Upiou: [64][1536][8], cols = [Ui|Uo|Uu]
    int v = u - 131072;
    int k8 = v / 1536, n = v - k8*1536;
    const float* U = (n < 512) ? Ui : (n < 1024) ? Uo : Uu;
    int c = n & 511;
    ushort8 pk;
    #pragma unroll
    for (int t = 0; t < 8; ++t) pk[t] = f2b(U[(size_t)(k8*8+t)*512 + c]);
    *(ushort8*)&Upiou[(size_t)v*8] = pk;
  } else {                     // Upf: [64][512][8]
    int v = u - 229376;
    int k8 = v >> 9, c = v & 511;
    ushort8 pk;
    #pragma unroll
    for (int t = 0; t < 8; ++t) pk[t] = f2b(Uf[(size_t)(k8*8+t)*512 + c]);
    *(ushort8*)&Upf[(size_t)v*8] = pk;
  }
  if (u < 2048) {              // bias, interleaved to match Wp
    int gate = (u >> 4) & 3;
    int d = ((u >> 6) << 4) | (u & 15);
    bias[u] = (gate == 0) ? bi[d] : (gate == 1) ? bfv[d] : (gate == 2) ? bo[d] : bu[d];
  }
}

// ---------------- gather emb rows -> X bf16 [22272][512] (level-padded) -----
__global__ void gather_x(const int* __restrict__ tok, const float* __restrict__ emb,
                         unsigned short* __restrict__ X)
{
  int u = blockIdx.x * blockDim.x + threadIdx.x;  // unit = 8 elems
  if (u >= 22272*64) return;
  int R = u >> 6, ch = u & 63;
  int l, node;
  if (R < 512)       { l = R >> 7; node = R & 127; int sz = 1 << (2*l); if (node >= sz) node = sz - 1; }
  else if (R < 768)  { l = 4; node = R - 512; }
  else if (R < 1792) { l = 5; node = R - 768; }
  else if (R < 5888) { l = 6; node = R - 1792; }
  else               { l = 7; node = R - 5888; }
  static const int offs_c[8] = {0,1,5,21,85,341,1365,5461};
  int tk = tok[offs_c[l] + node];
  const float* src = emb + (size_t)tk*512 + ch*8;
  ushort8 pk;
  #pragma unroll
  for (int t = 0; t < 8; ++t) pk[t] = f2b(src[t]);
  *(ushort8*)&X[(size_t)u*8] = pk;
}

// ------- hybrid bf16 MFMA GEMM: A via LDS dbuf, B direct from L2 -------------
struct GDesc {
  const unsigned short* A;   // [M][512] bf16 row-major
  const unsigned short* Bp;  // packed [64][N][8]
  ull* C;                    // fragment-packed (qaddr) output
  int M, N, NT;              // NT = N/128
};
struct L7P {                 // fused level-7 outputs (FUSED only)
  float* hout; unsigned short* hb; float* cb; unsigned short* ht;
};

template<bool FUSED>
__global__ __launch_bounds__(256, 4)
void gemm512(GDesc g1, GDesc g2, int split, const float* __restrict__ bias, L7P l7,
             float* __restrict__ zbase, size_t z4)
{
  __shared__ unsigned short As[2*128*64];   // 32 KB total (A only)

  const int nwg = gridDim.x, orig = blockIdx.x;
  const int q = nwg >> 3, r = nwg & 7;
  const int xcd = orig & 7, idx = orig >> 3;
  const int wg = (xcd < r ? xcd*(q+1) : r*(q+1) + (xcd-r)*q) + idx;

  const bool role1 = (wg < split);
  GDesc g = role1 ? g1 : g2;
  const int lwg = role1 ? wg : wg - split;
  const int tm = lwg / g.NT, tn = lwg - tm * g.NT;

  const int tid = threadIdx.x;
  const int wave = tid >> 6, lane = tid & 63;
  const int Mbase = tm * 128, Nbase = tn * 128;
  const int wr = wave >> 1, wc = wave & 1;
  const int l15 = lane & 15, l4 = lane >> 4;

  const int arow_l = wave*8 + (lane >> 3);
  const int acol8  = lane & 7;
  const int sw8    = arow_l & 7;

  f32x4 acc[4][4] = {};

  auto STAGE = [&](int p, int k0) {
    #pragma unroll
    for (int c = 0; c < 4; ++c) {
      int grow = Mbase + c*32 + arow_l;
      if (grow >= g.M) grow = g.M - 1;
      gl_lds16(g.A + (size_t)grow*512 + k0 + ((acol8 ^ sw8) * 8),
               As + p*(128*64) + (c*32 + wave*8)*64);
    }
  };

  auto COMPUTE = [&](int p, int k0) {
    #pragma unroll
    for (int ks = 0; ks < 2; ++ks) {
      bf16x8 af[4], bfr[4];
      #pragma unroll
      for (int nf = 0; nf < 4; ++nf)     // B direct from L2 (no barrier dep)
        bfr[nf] = *(const bf16x8*)(g.Bp +
            ((size_t)((k0 >> 3) + ks*4 + l4) * g.N + Nbase + wc*64 + nf*16 + l15) * 8);
      #pragma unroll
      for (int mf = 0; mf < 4; ++mf) {
        int row = wr*64 + mf*16 + l15;
        int kc  = ks*4 + l4;
        af[mf] = *(const bf16x8*)&As[p*(128*64) + row*64 + ((kc ^ (row & 7)) * 8)];
      }
      #pragma unroll
      for (int mf = 0; mf < 4; ++mf)
        #pragma unroll
        for (int nf = 0; nf < 4; ++nf)
          acc[mf][nf] = __builtin_amdgcn_mfma_f32_16x16x32_bf16(af[mf], bfr[nf], acc[mf][nf], 0, 0, 0);
    }
  };

  STAGE(0, 0);
  __syncthreads();
  #pragma unroll
  for (int it = 0; it < 7; ++it) {
    STAGE((it + 1) & 1, (it + 1) * 64);
    COMPUTE(it & 1, it * 64);
    __syncthreads();
  }
  COMPUTE(1, 448);

  if (FUSED && tm >= 46) {
    // ---- fused level-7 combine, in registers (leaves: c=i*u, h=o*tanh(c))
    const float bi_ = bias[Nbase + wc*64      + l15];
    const float bo_ = bias[Nbase + wc*64 + 32 + l15];
    const float bu_ = bias[Nbase + wc*64 + 48 + l15];
    const int d = tn*32 + wc*16 + l15;
    #pragma unroll
    for (int mf = 0; mf < 4; ++mf) {
      int node0 = Mbase - 5888 + wr*64 + mf*16 + l4*4;
      float hts = 0.f;
      #pragma unroll
      for (int rr = 0; rr < 4; ++rr) {
        float iv = sigmf(acc[mf][0][rr] + bi_);
        float ov = sigmf(acc[mf][2][rr] + bo_);
        float uv = tanhf(acc[mf][3][rr] + bu_);
        float cv = iv * uv;
        float hv = ov * tanhf(cv);
        size_t node = node0 + rr;
        l7.hout[node*512 + d] = hv;
        l7.hb[node*512 + d]   = f2b(hv);
        l7.cb[node*512 + d]   = cv;
        hts += hv;
      }
      l7.ht[(size_t)(node0 >> 2)*512 + d] = f2b(hts);
    }
  } else {
    float bv[4];
    #pragma unroll
    for (int nf = 0; nf < 4; ++nf)
      bv[nf] = (bias != nullptr && role1) ? bias[Nbase + wc*64 + nf*16 + l15] : 0.f;
    ull* Cb = g.C + ((size_t)(tm * g.NT + tn) << 12) + ((size_t)wave << 10);
    #pragma unroll
    for (int mf = 0; mf < 4; ++mf)
      #pragma unroll
      for (int nf = 0; nf < 4; ++nf) {
        f32x4 a = acc[mf][nf];
        ull pk = (ull)f2b(a[0] + bv[nf]) | ((ull)f2b(a[1] + bv[nf]) << 16)
               | ((ull)f2b(a[2] + bv[nf]) << 32) | ((ull)f2b(a[3] + bv[nf]) << 48);
        Cb[(mf*4 + nf)*64 + lane] = pk;
      }
  }

  if (zbase != nullptr) {       // leaf-region zeros on spare write BW
    f32x4 z = {0.f, 0.f, 0.f, 0.f};
    f32x4* zp = (f32x4*)zbase;
    size_t stride = (size_t)nwg * 256;
    for (size_t off = (size_t)orig*256 + tid; off < z4; off += stride) zp[off] = z;
  }
}

// ---------------- direct-register tile GEMM (small levels) -------------------
static DI void tile_gemm(const unsigned short* __restrict__ A, int M,
                         const unsigned short* __restrict__ Bp, int N, int NT,
                         int tm, int tn, ull* __restrict__ C, int wave, int lane)
{
  const int wr = wave >> 1, wc = wave & 1;
  const int l15 = lane & 15, l4 = lane >> 4;
  size_t a0[4]; unsigned int b0[4];
  #pragma unroll
  for (int mf = 0; mf < 4; ++mf) {
    int row = tm*128 + wr*64 + mf*16 + l15;
    if (row >= M) row = M - 1;
    a0[mf] = (size_t)row*512 + l4*8;
  }
  #pragma unroll
  for (int nf = 0; nf < 4; ++nf)
    b0[nf] = (unsigned int)(((unsigned)l4 * N + tn*128 + wc*64 + nf*16 + l15) * 8);
  const unsigned int bstep = (unsigned int)N * 32;

  f32x4 acc[4][4] = {};
  #pragma unroll
  for (int ks = 0; ks < 16; ++ks) {
    bf16x8 af[4], bfr[4];
    #pragma unroll
    for (int mf = 0; mf < 4; ++mf) af[mf] = *(const bf16x8*)(A + a0[mf] + ks*32);
    #pragma unroll
    for (int nf = 0; nf < 4; ++nf) bfr[nf] = *(const bf16x8*)(Bp + b0[nf] + ks*bstep);
    #pragma unroll
    for (int mf = 0; mf < 4; ++mf)
      #pragma unroll
      for (int nf = 0; nf < 4; ++nf)
        acc[mf][nf] = __builtin_amdgcn_mfma_f32_16x16x32_bf16(af[mf], bfr[nf], acc[mf][nf], 0, 0, 0);
  }
  ull* Cb = C + ((size_t)(tm * NT + tn) << 12) + ((size_t)wave << 10);
  #pragma unroll
  for (int mf = 0; mf < 4; ++mf)
    #pragma unroll
    for (int nf = 0; nf < 4; ++nf) {
      f32x4 a = acc[mf][nf];
      ull pk = (ull)f2b(a[0]) | ((ull)f2b(a[1]) << 16)
             | ((ull)f2b(a[2]) << 32) | ((ull)f2b(a[3]) << 48);
      Cb[(mf*4 + nf)*64 + lane] = pk;
    }
}

__global__ __launch_bounds__(256)
void gemm_small(GDesc g1, GDesc g2, int split)
{
  const int b = blockIdx.x;
  const bool role1 = (b < split);
  GDesc g = role1 ? g1 : g2;
  const int lb = role1 ? b : b - split;
  tile_gemm(g.A, g.M, g.Bp, g.N, g.NT, lb / g.NT, lb % g.NT, g.C,
            threadIdx.x >> 6, threadIdx.x & 63);
}

// ---------------- per-level elementwise combine (packed-C inputs) ------------
__global__ __launch_bounds__(256)
void combine2(const ull* __restrict__ Gq, const ull* __restrict__ Rq,
              const ull* __restrict__ Fq, const float* __restrict__ cch,
              float* __restrict__ hout, unsigned short* __restrict__ hbf,
              float* __restrict__ cout, unsigned short* __restrict__ htout,
              float* __restrict__ rootx, int n)
{
  const int b = blockIdx.x, t = threadIdx.x;
  #pragma unroll
  for (int half = 0; half < 2; ++half) {
    const int c = t + half * 256;
    ull gi4 = Gq[qaddr(16, b, GCOL(0, c))];
    ull gf4 = Gq[qaddr(16, b, GCOL(1, c))];
    ull go4 = Gq[qaddr(16, b, GCOL(2, c))];
    ull gu4 = Gq[qaddr(16, b, GCOL(3, c))];
    ull ri4 = Rq[qaddr(12, b, c)];
    ull ro4 = Rq[qaddr(12, b, c + 512)];
    ull ru4 = Rq[qaddr(12, b, c + 1024)];
    float hts = 0.f;
    #pragma unroll
    for (int rI = 0; rI < 4; ++rI) {
      int j = b*4 + rI;
      float gi = b2f((unsigned short)(gi4 >> (16*rI)));
      float gf = b2f((unsigned short)(gf4 >> (16*rI)));
      float go = b2f((unsigned short)(go4 >> (16*rI)));
      float gu = b2f((unsigned short)(gu4 >> (16*rI)));
      float iv = sigmf(gi + b2f((unsigned short)(ri4 >> (16*rI))));
      float ov = sigmf(go + b2f((unsigned short)(ro4 >> (16*rI))));
      float uv = tanhf(gu + b2f((unsigned short)(ru4 >> (16*rI))));
      ull f4 = Fq[qaddr(4, j, c)];
      const float* cc = cch + (size_t)(j*4)*512 + c;
      float fs = 0.f;
      #pragma unroll
      for (int k = 0; k < 4; ++k)
        fs += sigmf(gf + b2f((unsigned short)(f4 >> (16*k)))) * cc[(size_t)k*512];
      float cv = iv*uv + fs;
      float hv = ov * tanhf(cv);
      if (j < n) {
        hout[(size_t)j*512 + c] = hv;
        hbf[(size_t)j*512 + c]  = f2b(hv);
        cout[(size_t)j*512 + c] = cv;
        if (rootx && j == 0) { rootx[c] = hv; rootx[512 + c] = cv; }
        hts += hv;
      }
    }
    if (htout) htout[(size_t)b*512 + c] = f2b(hts);
  }
}

// ---------------- launch -----------------------------------------------------
extern "C" void kernel_launch(void* const* d_in, const int* in_sizes, int n_in,
                              void* d_out, int out_size, void* d_ws, size_t ws_size,
                              hipStream_t stream)
{
  const int*   tok = (const int*)d_in[0];
  const float* emb = (const float*)d_in[1];
  const float* Wi  = (const float*)d_in[2];
  const float* Ui  = (const float*)d_in[3];
  const float* bi  = (const float*)d_in[4];
  const float* Wf  = (const float*)d_in[5];
  const float* Uf  = (const float*)d_in[6];
  const float* bfv = (const float*)d_in[7];
  const float* Wo  = (const float*)d_in[8];
  const float* Uo  = (const float*)d_in[9];
  const float* bo  = (const float*)d_in[10];
  const float* Wu  = (const float*)d_in[11];
  const float* Uu  = (const float*)d_in[12];
  const float* bu  = (const float*)d_in[13];

  char* ws = (char*)d_ws;
  unsigned short* Wp    = (unsigned short*)(ws + 0);           //  2,097,152
  unsigned short* Upiou = (unsigned short*)(ws + 2097152);     //  1,572,864
  unsigned short* Upf   = (unsigned short*)(ws + 3670016);     //    524,288
  float*          bias  = (float*)        (ws + 4194304);      //      8,192
  unsigned short* hbf   = (unsigned short*)(ws + 4202752);     // 22,369,280
  unsigned short* htbf  = (unsigned short*)(ws + 26572032);    //  5,592,064
  float*          cbuf  = (float*)        (ws + 32164096);     // 44,738,560
  ull*            RiouQ = (ull*)          (ws + 76902656);     // 12,582,912
  ull*            RfQ   = (ull*)          (ws + 89485568);     // 16,777,216
  ull*            Gq    = (ull*)          (ws + 106262784);    // 24,117,248 (46 row-tiles)
  unsigned short* X     = (unsigned short*)(ws + 130380032);   // 22,806,528 -> 153,186,560

  float* fout = (float*)d_out;

  static const int  offs[9]    = {0,1,5,21,85,341,1365,5461,21845};
  static const int  padbase[8] = {0,128,256,384,512,768,1792,5888};
  static const long outoff[8]  = {87380,87376,87360,87296,87040,86016,81920,65536};

  prep_pack<<<1024, 256, 0, stream>>>(Wi,Ui,bi,Wf,Uf,bfv,Wo,Uo,bo,Wu,Uu,bu,
                                      Wp,Upiou,Upf,bias);
  gather_x<<<(22272*64)/256, 256, 0, stream>>>(tok, emb, X);

  // big GEMM: gates for all internal nodes; fused level-7 combine (register)
  GDesc gA { X, Wp, Gq, 22272, 2048, 16 };
  L7P l7 { fout + (size_t)outoff[7]*512, hbf + (size_t)offs[7]*512,
           cbuf + (size_t)offs[7]*512, htbf + (size_t)offs[6]*512 };
  gemm512<true><<<174*16, 256, 0, stream>>>(gA, gA, 174*16, bias, l7, nullptr, 0);

  L7P l7n {};
  // level 6 (carries the 134 MB leaf zero-fill on spare write BW)
  {
    GDesc g1 { htbf + (size_t)offs[6]*512, Upiou, RiouQ, 4096,  1536, 12 };
    GDesc g2 { hbf  + (size_t)offs[7]*512, Upf,   RfQ,   16384, 512,  4  };
    gemm512<false><<<32*12 + 128*4, 256, 0, stream>>>(g1, g2, 32*12, nullptr, l7n,
                                                      fout, (size_t)65536*512/4);
    combine2<<<1024, 256, 0, stream>>>(
        Gq + (size_t)padbase[6]*512, RiouQ, RfQ, cbuf + (size_t)offs[7]*512,
        fout + (size_t)outoff[6]*512, hbf + (size_t)offs[6]*512, cbuf + (size_t)offs[6]*512,
        htbf + (size_t)offs[5]*512, nullptr, 4096);
  }
  // level 5
  {
    GDesc g1 { htbf + (size_t)offs[5]*512, Upiou, RiouQ, 1024, 1536, 12 };
    GDesc g2 { hbf  + (size_t)offs[6]*512, Upf,   RfQ,   4096, 512,  4  };
    gemm512<false><<<8*12 + 32*4, 256, 0, stream>>>(g1, g2, 8*12, nullptr, l7n, nullptr, 0);
    combine2<<<256, 256, 0, stream>>>(
        Gq + (size_t)padbase[5]*512, RiouQ, RfQ, cbuf + (size_t)offs[6]*512,
        fout + (size_t)outoff[5]*512, hbf + (size_t)offs[5]*512, cbuf + (size_t)offs[5]*512,
        htbf + (size_t)offs[4]*512, nullptr, 1024);
  }
  // levels 4..0: direct-register tile GEMM + combine, 2 launches per level
  for (int l = 4; l >= 0; --l) {
    int n = 1 << (2*l);
    int t1 = ((n + 127) >> 7) * 12;
    int t2 = ((4*n + 127) >> 7) * 4;
    GDesc g1 { htbf + (size_t)offs[l]*512,   Upiou, RiouQ, n,   1536, 12 };
    GDesc g2 { hbf  + (size_t)offs[l+1]*512, Upf,   RfQ,   4*n, 512,  4  };
    gemm_small<<<t1 + t2, 256, 0, stream>>>(g1, g2, t1);
    combine2<<<(n + 3) / 4, 256, 0, stream>>>(
        Gq + (size_t)padbase[l]*512, RiouQ, RfQ, cbuf + (size_t)offs[l+1]*512,
        fout + (size_t)outoff[l]*512, hbf + (size_t)offs[l]*512, cbuf + (size_t)offs[l]*512,
        (l > 0) ? htbf + (size_t)offs[l-1]*512 : nullptr,
        (l == 0) ? fout + (size_t)87381*512 : nullptr,
        n);
  }
}

// Round 12
// 269.064 us; speedup vs baseline: 2.2484x; 1.0330x over previous
//
#include <hip/hip_runtime.h>

#define DI __device__ __forceinline__

typedef __attribute__((ext_vector_type(8))) __bf16 bf16x8;
typedef __attribute__((ext_vector_type(4))) float f32x4;
typedef __attribute__((ext_vector_type(8))) unsigned short ushort8;
typedef unsigned long long ull;

static DI unsigned short f2b(float f) {
  unsigned int x = __builtin_bit_cast(unsigned int, f);
  unsigned int r = (x + 0x7FFFu + ((x >> 16) & 1u)) >> 16;
  return (unsigned short)r;
}
static DI float b2f(unsigned short u) {
  return __builtin_bit_cast(float, (unsigned int)u << 16);
}
static DI float sigmf(float x) { return 1.0f / (1.0f + __expf(-x)); }

typedef const __attribute__((address_space(1))) void* gcptr;
typedef __attribute__((address_space(3))) void* lptr;
static DI void gl_lds16(const void* g, void* l) {
  __builtin_amdgcn_global_load_lds((gcptr)g, (lptr)l, 16, 0, 0);
}

// gate-interleaved column (16-granular): gate g, dim d -> raw col in [0,2048)
#define GCOL(g, d) ((((d) >> 4) << 6) + ((g) << 4) + ((d) & 15))

// packed-C quad address (b64 units): rows 4*row4..4*row4+3, col c; NT = N/128
static DI size_t qaddr(int NT, int row4, int c) {
  int tm = row4 >> 5, tn = c >> 7;
  int rq = row4 & 31, c7 = c & 127;
  int wv = ((rq >> 4) << 1) | (c7 >> 6);
  int mf = (rq >> 2) & 3, nf = (c7 >> 4) & 3;
  int lane = ((rq & 3) << 4) | (c7 & 15);
  return ((size_t)(tm * NT + tn) << 12) + (size_t)((((wv << 4) + (mf << 2) + nf) << 6) + lane);
}

// ---------------- weight packing ---------------------------------------------
__global__ void prep_pack(const float* __restrict__ Wi, const float* __restrict__ Ui,
                          const float* __restrict__ bi, const float* __restrict__ Wf,
                          const float* __restrict__ Uf, const float* __restrict__ bfv,
                          const float* __restrict__ Wo, const float* __restrict__ Uo,
                          const float* __restrict__ bo, const float* __restrict__ Wu,
                          const float* __restrict__ Uu, const float* __restrict__ bu,
                          unsigned short* __restrict__ Wp, unsigned short* __restrict__ Upiou,
                          unsigned short* __restrict__ Upf, float* __restrict__ bias)
{
  int u = blockIdx.x * blockDim.x + threadIdx.x;  // 0..262143
  if (u < 131072) {            // Wp: [64][2048][8], 16-granular gate-interleaved cols
    int k8 = u >> 11, n = u & 2047;
    int gate = (n >> 4) & 3;
    int d = ((n >> 6) << 4) | (n & 15);
    const float* W = (gate == 0) ? Wi : (gate == 1) ? Wf : (gate == 2) ? Wo : Wu;
    ushort8 pk;
    #pragma unroll
    for (int t = 0; t < 8; ++t) pk[t] = f2b(W[(size_t)(k8*8+t)*512 + d]);
    *(ushort8*)&Wp[(size_t)u*8] = pk;
  } else if (u < 131072 + 98304) {  // Upiou: [64][1536][8], cols = [Ui|Uo|Uu]
    int v = u - 131072;
    int k8 = v / 1536, n = v - k8*1536;
    const float* U = (n < 512) ? Ui : (n < 1024) ? Uo : Uu;
    int c = n & 511;
    ushort8 pk;
    #pragma unroll
    for (int t = 0; t < 8; ++t) pk[t] = f2b(U[(size_t)(k8*8+t)*512 + c]);
    *(ushort8*)&Upiou[(size_t)v*8] = pk;
  } else {                     // Upf: [64][512][8]
    int v = u - 229376;
    int k8 = v >> 9, c = v & 511;
    ushort8 pk;
    #pragma unroll
    for (int t = 0; t < 8; ++t) pk[t] = f2b(Uf[(size_t)(k8*8+t)*512 + c]);
    *(ushort8*)&Upf[(size_t)v*8] = pk;
  }
  if (u < 2048) {              // bias, interleaved to match Wp
    int gate = (u >> 4) & 3;
    int d = ((u >> 6) << 4) | (u & 15);
    bias[u] = (gate == 0) ? bi[d] : (gate == 1) ? bfv[d] : (gate == 2) ? bo[d] : bu[d];
  }
}

// ---------------- gather emb rows -> X bf16 [22272][512] (level-padded) -----
__global__ void gather_x(const int* __restrict__ tok, const float* __restrict__ emb,
                         unsigned short* __restrict__ X)
{
  int u = blockIdx.x * blockDim.x + threadIdx.x;  // unit = 8 elems
  if (u >= 22272*64) return;
  int R = u >> 6, ch = u & 63;
  int l, node;
  if (R < 512)       { l = R >> 7; node = R & 127; int sz = 1 << (2*l); if (node >= sz) node = sz - 1; }
  else if (R < 768)  { l = 4; node = R - 512; }
  else if (R < 1792) { l = 5; node = R - 768; }
  else if (R < 5888) { l = 6; node = R - 1792; }
  else               { l = 7; node = R - 5888; }
  static const int offs_c[8] = {0,1,5,21,85,341,1365,5461};
  int tk = tok[offs_c[l] + node];
  const float* src = emb + (size_t)tk*512 + ch*8;
  ushort8 pk;
  #pragma unroll
  for (int t = 0; t < 8; ++t) pk[t] = f2b(src[t]);
  *(ushort8*)&X[(size_t)u*8] = pk;
}

// ------- hybrid bf16 MFMA GEMM: A via LDS dbuf, B direct from L2 -------------
struct GDesc {
  const unsigned short* A;   // [M][512] bf16 row-major
  const unsigned short* Bp;  // packed [64][N][8]
  ull* C;                    // fragment-packed (qaddr) output
  int M, N, NT;              // NT = N/128
};
struct L7P {                 // fused level-7 outputs (FUSED only)
  float* hout; unsigned short* hb; float* cb; unsigned short* ht;
};

template<bool FUSED>
__global__ __launch_bounds__(256, 4)
void gemm512(GDesc g1, GDesc g2, int split, const float* __restrict__ bias, L7P l7,
             float* __restrict__ zbase, size_t z4)
{
  __shared__ unsigned short As[2*128*64];   // 32 KB total (A only)

  const int nwg = gridDim.x, orig = blockIdx.x;
  const int q = nwg >> 3, r = nwg & 7;
  const int xcd = orig & 7, idx = orig >> 3;
  const int wg = (xcd < r ? xcd*(q+1) : r*(q+1) + (xcd-r)*q) + idx;

  const bool role1 = (wg < split);
  GDesc g = role1 ? g1 : g2;
  const int lwg = role1 ? wg : wg - split;
  const int tm = lwg / g.NT, tn = lwg - tm * g.NT;

  const int tid = threadIdx.x;
  const int wave = tid >> 6, lane = tid & 63;
  const int Mbase = tm * 128, Nbase = tn * 128;
  const int wr = wave >> 1, wc = wave & 1;
  const int l15 = lane & 15, l4 = lane >> 4;

  const int arow_l = wave*8 + (lane >> 3);
  const int acol8  = lane & 7;
  const int sw8    = arow_l & 7;

  f32x4 acc[4][4] = {};

  auto STAGE = [&](int p, int k0) {
    #pragma unroll
    for (int c = 0; c < 4; ++c) {
      int grow = Mbase + c*32 + arow_l;
      if (grow >= g.M) grow = g.M - 1;
      gl_lds16(g.A + (size_t)grow*512 + k0 + ((acol8 ^ sw8) * 8),
               As + p*(128*64) + (c*32 + wave*8)*64);
    }
  };

  auto COMPUTE = [&](int p, int k0) {
    #pragma unroll
    for (int ks = 0; ks < 2; ++ks) {
      bf16x8 af[4], bfr[4];
      #pragma unroll
      for (int nf = 0; nf < 4; ++nf)     // B direct from L2 (no barrier dep)
        bfr[nf] = *(const bf16x8*)(g.Bp +
            ((size_t)((k0 >> 3) + ks*4 + l4) * g.N + Nbase + wc*64 + nf*16 + l15) * 8);
      #pragma unroll
      for (int mf = 0; mf < 4; ++mf) {
        int row = wr*64 + mf*16 + l15;
        int kc  = ks*4 + l4;
        af[mf] = *(const bf16x8*)&As[p*(128*64) + row*64 + ((kc ^ (row & 7)) * 8)];
      }
      #pragma unroll
      for (int mf = 0; mf < 4; ++mf)
        #pragma unroll
        for (int nf = 0; nf < 4; ++nf)
          acc[mf][nf] = __builtin_amdgcn_mfma_f32_16x16x32_bf16(af[mf], bfr[nf], acc[mf][nf], 0, 0, 0);
    }
  };

  STAGE(0, 0);
  __syncthreads();
  #pragma unroll
  for (int it = 0; it < 7; ++it) {
    STAGE((it + 1) & 1, (it + 1) * 64);
    COMPUTE(it & 1, it * 64);
    __syncthreads();
  }
  COMPUTE(1, 448);

  if (FUSED && tm >= 46) {
    // ---- fused level-7 combine, in registers (leaves: c=i*u, h=o*tanh(c))
    const float bi_ = bias[Nbase + wc*64      + l15];
    const float bo_ = bias[Nbase + wc*64 + 32 + l15];
    const float bu_ = bias[Nbase + wc*64 + 48 + l15];
    const int d = tn*32 + wc*16 + l15;
    #pragma unroll
    for (int mf = 0; mf < 4; ++mf) {
      int node0 = Mbase - 5888 + wr*64 + mf*16 + l4*4;
      float hts = 0.f;
      #pragma unroll
      for (int rr = 0; rr < 4; ++rr) {
        float iv = sigmf(acc[mf][0][rr] + bi_);
        float ov = sigmf(acc[mf][2][rr] + bo_);
        float uv = tanhf(acc[mf][3][rr] + bu_);
        float cv = iv * uv;
        float hv = ov * tanhf(cv);
        size_t node = node0 + rr;
        l7.hout[node*512 + d] = hv;
        l7.hb[node*512 + d]   = f2b(hv);
        l7.cb[node*512 + d]   = cv;
        hts += hv;
      }
      l7.ht[(size_t)(node0 >> 2)*512 + d] = f2b(hts);
    }
  } else {
    float bv[4];
    #pragma unroll
    for (int nf = 0; nf < 4; ++nf)
      bv[nf] = (bias != nullptr && role1) ? bias[Nbase + wc*64 + nf*16 + l15] : 0.f;
    ull* Cb = g.C + ((size_t)(tm * g.NT + tn) << 12) + ((size_t)wave << 10);
    #pragma unroll
    for (int mf = 0; mf < 4; ++mf)
      #pragma unroll
      for (int nf = 0; nf < 4; ++nf) {
        f32x4 a = acc[mf][nf];
        ull pk = (ull)f2b(a[0] + bv[nf]) | ((ull)f2b(a[1] + bv[nf]) << 16)
               | ((ull)f2b(a[2] + bv[nf]) << 32) | ((ull)f2b(a[3] + bv[nf]) << 48);
        Cb[(mf*4 + nf)*64 + lane] = pk;
      }
  }

  if (FUSED && zbase != nullptr) {   // leaf-region zeros spread over all blocks
    size_t b4 = (size_t)orig * 3072;
    f32x4 z = {0.f, 0.f, 0.f, 0.f};
    f32x4* zp = (f32x4*)zbase;
    #pragma unroll
    for (int i = 0; i < 12; ++i) {
      size_t off = b4 + (size_t)i*256 + tid;
      if (off < z4) zp[off] = z;
    }
  }
}

// ---------------- per-level elementwise combine (packed-C inputs) ------------
__global__ __launch_bounds__(256)
void combine2(const ull* __restrict__ Gq, const ull* __restrict__ Rq,
              const ull* __restrict__ Fq, const float* __restrict__ cch,
              float* __restrict__ hout, unsigned short* __restrict__ hbf,
              float* __restrict__ cout, unsigned short* __restrict__ htout,
              float* __restrict__ rootx, int n)
{
  const int b = blockIdx.x, t = threadIdx.x;
  #pragma unroll
  for (int half = 0; half < 2; ++half) {
    const int c = t + half * 256;
    ull gi4 = Gq[qaddr(16, b, GCOL(0, c))];
    ull gf4 = Gq[qaddr(16, b, GCOL(1, c))];
    ull go4 = Gq[qaddr(16, b, GCOL(2, c))];
    ull gu4 = Gq[qaddr(16, b, GCOL(3, c))];
    ull ri4 = Rq[qaddr(12, b, c)];
    ull ro4 = Rq[qaddr(12, b, c + 512)];
    ull ru4 = Rq[qaddr(12, b, c + 1024)];
    float hts = 0.f;
    #pragma unroll
    for (int rI = 0; rI < 4; ++rI) {
      int j = b*4 + rI;
      float gi = b2f((unsigned short)(gi4 >> (16*rI)));
      float gf = b2f((unsigned short)(gf4 >> (16*rI)));
      float go = b2f((unsigned short)(go4 >> (16*rI)));
      float gu = b2f((unsigned short)(gu4 >> (16*rI)));
      float iv = sigmf(gi + b2f((unsigned short)(ri4 >> (16*rI))));
      float ov = sigmf(go + b2f((unsigned short)(ro4 >> (16*rI))));
      float uv = tanhf(gu + b2f((unsigned short)(ru4 >> (16*rI))));
      ull f4 = Fq[qaddr(4, j, c)];
      const float* cc = cch + (size_t)(j*4)*512 + c;
      float fs = 0.f;
      #pragma unroll
      for (int k = 0; k < 4; ++k)
        fs += sigmf(gf + b2f((unsigned short)(f4 >> (16*k)))) * cc[(size_t)k*512];
      float cv = iv*uv + fs;
      float hv = ov * tanhf(cv);
      if (j < n) {
        hout[(size_t)j*512 + c] = hv;
        hbf[(size_t)j*512 + c]  = f2b(hv);
        cout[(size_t)j*512 + c] = cv;
        if (rootx && j == 0) { rootx[c] = hv; rootx[512 + c] = cv; }
        hts += hv;
      }
    }
    if (htout) htout[(size_t)b*512 + c] = f2b(hts);
  }
}

// ---------------- launch -----------------------------------------------------
extern "C" void kernel_launch(void* const* d_in, const int* in_sizes, int n_in,
                              void* d_out, int out_size, void* d_ws, size_t ws_size,
                              hipStream_t stream)
{
  const int*   tok = (const int*)d_in[0];
  const float* emb = (const float*)d_in[1];
  const float* Wi  = (const float*)d_in[2];
  const float* Ui  = (const float*)d_in[3];
  const float* bi  = (const float*)d_in[4];
  const float* Wf  = (const float*)d_in[5];
  const float* Uf  = (const float*)d_in[6];
  const float* bfv = (const float*)d_in[7];
  const float* Wo  = (const float*)d_in[8];
  const float* Uo  = (const float*)d_in[9];
  const float* bo  = (const float*)d_in[10];
  const float* Wu  = (const float*)d_in[11];
  const float* Uu  = (const float*)d_in[12];
  const float* bu  = (const float*)d_in[13];

  char* ws = (char*)d_ws;
  unsigned short* Wp    = (unsigned short*)(ws + 0);           //  2,097,152
  unsigned short* Upiou = (unsigned short*)(ws + 2097152);     //  1,572,864
  unsigned short* Upf   = (unsigned short*)(ws + 3670016);     //    524,288
  float*          bias  = (float*)        (ws + 4194304);      //      8,192
  unsigned short* hbf   = (unsigned short*)(ws + 4202752);     // 22,369,280
  unsigned short* htbf  = (unsigned short*)(ws + 26572032);    //  5,592,064
  float*          cbuf  = (float*)        (ws + 32164096);     // 44,738,560
  ull*            RiouQ = (ull*)          (ws + 76902656);     // 12,582,912
  ull*            RfQ   = (ull*)          (ws + 89485568);     // 16,777,216
  ull*            Gq    = (ull*)          (ws + 106262784);    // 24,117,248 (46 row-tiles)
  unsigned short* X     = (unsigned short*)(ws + 130380032);   // 22,806,528 -> 153,186,560

  float* fout = (float*)d_out;

  static const int  offs[9]    = {0,1,5,21,85,341,1365,5461,21845};
  static const int  padbase[8] = {0,128,256,384,512,768,1792,5888};
  static const long outoff[8]  = {87380,87376,87360,87296,87040,86016,81920,65536};

  prep_pack<<<1024, 256, 0, stream>>>(Wi,Ui,bi,Wf,Uf,bfv,Wo,Uo,bo,Wu,Uu,bu,
                                      Wp,Upiou,Upf,bias);
  gather_x<<<(22272*64)/256, 256, 0, stream>>>(tok, emb, X);

  // big GEMM: gates for all internal nodes; fused level-7 combine + leaf zeros
  GDesc gA { X, Wp, Gq, 22272, 2048, 16 };
  L7P l7 { fout + (size_t)outoff[7]*512, hbf + (size_t)offs[7]*512,
           cbuf + (size_t)offs[7]*512, htbf + (size_t)offs[6]*512 };
  gemm512<true><<<174*16, 256, 0, stream>>>(gA, gA, 174*16, bias, l7,
                                            fout, (size_t)65536*512/4);

  L7P l7n {};
  // levels 6..0: hybrid gemm + combine per level
  for (int l = 6; l >= 0; --l) {
    int n = 1 << (2*l);
    int tm1 = (n + 127) / 128, tm2 = (4*n + 127) / 128;
    int split = tm1 * 12;
    GDesc g1 { htbf + (size_t)offs[l]*512,   Upiou, RiouQ, n,   1536, 12 };
    GDesc g2 { hbf  + (size_t)offs[l+1]*512, Upf,   RfQ,   4*n, 512,  4  };
    gemm512<false><<<split + tm2*4, 256, 0, stream>>>(g1, g2, split, nullptr, l7n,
                                                      nullptr, 0);
    combine2<<<(n + 3) / 4, 256, 0, stream>>>(
        Gq + (size_t)padbase[l]*512, RiouQ, RfQ, cbuf + (size_t)offs[l+1]*512,
        fout + (size_t)outoff[l]*512, hbf + (size_t)offs[l]*512, cbuf + (size_t)offs[l]*512,
        (l > 0) ? htbf + (size_t)offs[l-1]*512 : nullptr,
        (l == 0) ? fout + (size_t)87381*512 : nullptr,
        n);
  }
}